// Round 13
// baseline (618.110 us; speedup 1.0000x reference)
//
#include <hip/hip_runtime.h>
#include <math.h>

#define NPOS 131072  // 8*128*128 spatial positions per (b, channel)
#define GC 128       // gram chunks per (b,head); chunk = 1024 positions

// ---------------------------------------------------------------------------
// k_prep: transpose w_qkv [192 out][64 in] -> wT[3 g][64 k][64 o].
// ---------------------------------------------------------------------------
__global__ void k_prep(const float* __restrict__ w_qkv, float* __restrict__ wT) {
  for (int i = blockIdx.x * 256 + threadIdx.x; i < 12288; i += 512) {
    int g = i >> 12, r = i & 4095, k = r >> 6, o = r & 63;
    wT[i] = w_qkv[(g * 64 + o) * 64 + k];
  }
}

// ---------------------------------------------------------------------------
// k_pw: pre[b][o][p] = sum_k wTg[k][o] * x[b][k][p].
// LDS-x design (r10-r12 lesson: compiler fissions big-accumulator loops and
// re-reads the source; make the re-read cheap instead of fighting regalloc).
// block (64,4) = 64 positions x 4 o-groups; stage x tile [64 ch][64 pos]
// (16 KB) via coalesced float4; compute: 64 x {1 conflict-free ds_read_b32 +
// 16 FMA with SGPR weights}. grid (2048, 2).
// ---------------------------------------------------------------------------
__global__ __launch_bounds__(256) void k_pw(const float* __restrict__ x,
                                            const float* __restrict__ wTg,
                                            float* __restrict__ pre) {
  const int p0 = blockIdx.x * 64;
  const int b = blockIdx.y;
  const int tx = threadIdx.x;   // position within tile
  const int og = threadIdx.y;   // o-group (wave-uniform)
  __shared__ __align__(16) float xl[64][64];
  const float* xb = x + ((size_t)b * 64) * NPOS + p0;
  const int tid = og * 64 + tx;
#pragma unroll
  for (int r = 0; r < 4; ++r) {
    int idx = r * 256 + tid;          // 0..1023
    int ch = idx >> 4;
    int j4 = (idx & 15) * 4;
    *(float4*)&xl[ch][j4] = *(const float4*)&xb[(size_t)ch * NPOS + j4];
  }
  __syncthreads();
  float acc[16];
#pragma unroll
  for (int o = 0; o < 16; ++o) acc[o] = 0.f;
  const float* wb = wTg + og * 16;
  for (int k = 0; k < 64; ++k) {
    float xv = xl[k][tx];
    const float* wr = wb + (k << 6);  // wave-uniform -> s_load
#pragma unroll
    for (int o = 0; o < 16; ++o) acc[o] = fmaf(wr[o], xv, acc[o]);
  }
  float* ob = pre + ((size_t)b * 64 + og * 16) * NPOS + p0 + tx;
#pragma unroll
  for (int o = 0; o < 16; ++o) ob[(size_t)o * NPOS] = acc[o];
}

// ---------------------------------------------------------------------------
// stage_tile: one channel's halo tile -> LDS t[10][10][40]. float4 center,
// scalar edges, zero d-halo planes.
// ---------------------------------------------------------------------------
__device__ __forceinline__ void stage_tile(float (*t)[10][40], const float* __restrict__ in,
                                           int h0, int w0, int tid) {
  for (int i = tid; i < 800; i += 256) {
    int j = i & 7, row = i >> 3;
    int h = row % 10, dpl = row / 10;
    int dd = dpl - 1, hh = h0 + h - 1;
    float4 v = make_float4(0.f, 0.f, 0.f, 0.f);
    if (dd >= 0 && dd < 8 && hh >= 0 && hh < 128)
      v = *(const float4*)&in[((size_t)dd * 128 + hh) * 128 + (w0 + j * 4)];
    *(float4*)&t[dpl][h][4 + j * 4] = v;
  }
  for (int i = tid; i < 200; i += 256) {
    int side = i & 1, row = i >> 1;
    int h = row % 10, dpl = row / 10;
    int dd = dpl - 1, hh = h0 + h - 1;
    int ww = side ? (w0 + 32) : (w0 - 1);
    float v = 0.f;
    if (dd >= 0 && dd < 8 && hh >= 0 && hh < 128 && ww >= 0 && ww < 128)
      v = in[((size_t)dd * 128 + hh) * 128 + ww];
    t[dpl][h][side ? 36 : 3] = v;
  }
}

// ---------------------------------------------------------------------------
// conv_droll: d-rolling 3x3x3 conv: 90 LDS reads, 216 FMA for 8 d-outputs.
// ---------------------------------------------------------------------------
__device__ __forceinline__ void conv_droll(const float (*t)[10][40], const float* wk,
                                           int hl, int wl, float* acc) {
#pragma unroll
  for (int d = 0; d < 8; ++d) acc[d] = 0.f;
#pragma unroll
  for (int dpl = 0; dpl < 10; ++dpl) {
#pragma unroll
    for (int kh = 0; kh < 3; ++kh) {
#pragma unroll
      for (int kw = 0; kw < 3; ++kw) {
        float f = t[dpl][hl + kh][3 + wl + kw];
#pragma unroll
        for (int kd = 0; kd < 3; ++kd) {
          const int d = dpl - kd;
          if (d >= 0 && d < 8)
            acc[d] = fmaf(f, wk[(kd * 3 + kh) * 3 + kw], acc[d]);
        }
      }
    }
  }
}

// ---------------------------------------------------------------------------
// k_dw: depthwise 3x3x3 SAME on a 64-channel group. Flat grid 8192,
// XCD-swizzled. block (32, 8). Optional sum-of-squares partials -> nsq.
// ---------------------------------------------------------------------------
__global__ __launch_bounds__(256) void k_dw(const float* __restrict__ pre,
                                            const float* __restrict__ w_dw,
                                            float* __restrict__ conv,
                                            float* __restrict__ nsq, int g) {
  const int id = blockIdx.x;
  const int sid = (id & 7) * 1024 + (id >> 3);
  const int z = sid >> 6, r = sid & 63, by = r >> 2, bx = r & 3;
  const int b = z >> 6;
  const int c = z & 63;
  const int h0 = by * 8;
  const int w0 = bx * 32;
  __shared__ float t[10][10][40];
  __shared__ float red[4];
  const int tid = threadIdx.y * 32 + threadIdx.x;
  stage_tile(t, pre + ((size_t)b * 64 + c) * NPOS, h0, w0, tid);
  float wk[27];
#pragma unroll
  for (int i = 0; i < 27; ++i) wk[i] = w_dw[(g * 64 + c) * 27 + i];
  __syncthreads();
  const int wl = threadIdx.x, hl = threadIdx.y;
  float acc[8];
  conv_droll(t, wk, hl, wl, acc);
  float* outp = conv + ((size_t)b * 64 + c) * NPOS + (size_t)(h0 + hl) * 128 + (w0 + wl);
  float nsum = 0.f;
#pragma unroll
  for (int d = 0; d < 8; ++d) {
    outp[(size_t)d * 16384] = acc[d];
    nsum = fmaf(acc[d], acc[d], nsum);
  }
  if (nsq) {
    const int lane = tid & 63, wv = tid >> 6;
    float v = nsum;
    v += __shfl_down(v, 32); v += __shfl_down(v, 16); v += __shfl_down(v, 8);
    v += __shfl_down(v, 4);  v += __shfl_down(v, 2);  v += __shfl_down(v, 1);
    if (lane == 0) red[wv] = v;
    __syncthreads();
    if (tid == 0) {
      const int blk = by * 4 + bx;
      nsq[((size_t)b * 64 + c) * 64 + blk] = red[0] + red[1] + red[2] + red[3];
    }
  }
}

// ---------------------------------------------------------------------------
// k_gramS: streaming Gram reduce, S[8][8] only (norms come from k_dw).
// grid (GC, 16 bh), block 256; 4 unrolled iterations of {16 loads -> 64 FMA};
// asm guards pin S. Butterfly-split reduction (63 shuffles) -> lane l holds
// wave sum of S[bitrev6(l)]. partialS[(bh*GC + chunk)*64 + c*8+e].
// ---------------------------------------------------------------------------
__global__ __launch_bounds__(256) void k_gramS(const float* __restrict__ qconv,
                                               const float* __restrict__ kconv,
                                               float* __restrict__ partialS) {
  const int chunk = blockIdx.x;   // 0..GC-1
  const int bh = blockIdx.y;      // 0..15
  const int b = bh >> 3, head = bh & 7;
  const int tid = threadIdx.x;
  const size_t base = ((size_t)b * 64 + head * 8) * NPOS + (size_t)chunk * 1024 + tid;
  const float* qb = qconv + base;
  const float* kb = kconv + base;
  float S[64];
#pragma unroll
  for (int i = 0; i < 64; ++i) S[i] = 0.f;
#pragma unroll
  for (int it = 0; it < 4; ++it) {
    const size_t off = (size_t)it * 256;
    float qv[8], kv[8];
#pragma unroll
    for (int c = 0; c < 8; ++c) qv[c] = qb[(size_t)c * NPOS + off];
#pragma unroll
    for (int e = 0; e < 8; ++e) kv[e] = kb[(size_t)e * NPOS + off];
#pragma unroll
    for (int c = 0; c < 8; ++c)
#pragma unroll
      for (int e = 0; e < 8; ++e) S[c * 8 + e] = fmaf(qv[c], kv[e], S[c * 8 + e]);
  }
#pragma unroll
  for (int i = 0; i < 64; ++i) asm volatile("" : "+v"(S[i]));  // keep S material

  const int lane = tid & 63, wv = tid >> 6;
#define BSTEP(src, dst, n, s)                                        \
  {                                                                  \
    const bool hi_ = (lane >> (s)) & 1;                              \
    _Pragma("unroll")                                                \
    for (int i_ = 0; i_ < (n); ++i_) {                               \
      float send_ = hi_ ? src[i_] : src[i_ + (n)];                   \
      float mine_ = hi_ ? src[i_ + (n)] : src[i_];                   \
      dst[i_] = mine_ + __shfl_xor(send_, 1 << (s));                 \
    }                                                                \
  }
  float v32[32], v16[16], v8[8], v4[4], v2[2], v1[1];
  BSTEP(S,   v32, 32, 0)
  BSTEP(v32, v16, 16, 1)
  BSTEP(v16, v8,   8, 2)
  BSTEP(v8,  v4,   4, 3)
  BSTEP(v4,  v2,   2, 4)
  BSTEP(v2,  v1,   1, 5)
#undef BSTEP
  const int idx = ((lane & 1) << 5) | ((lane & 2) << 3) | ((lane & 4) << 1) |
                  ((lane & 8) >> 1) | ((lane & 16) >> 3) | ((lane & 32) >> 5);
  __shared__ float red[4][64];
  red[wv][idx] = v1[0];
  __syncthreads();
  if (tid < 64) {
    float s = red[0][tid] + red[1][tid] + red[2][tid] + red[3][tid];
    partialS[((size_t)bh * GC + chunk) * 64 + tid] = s;
  }
}

// ---------------------------------------------------------------------------
// k_attn: reduce partialS (GC chunks) + nqp/nkp (64 spatial blocks),
// l2-normalize, temperature, softmax -> A[bh][c][e]. grid 16, block 128.
// ---------------------------------------------------------------------------
__global__ void k_attn(const float* __restrict__ partialS, const float* __restrict__ nqp,
                       const float* __restrict__ nkp, const float* __restrict__ temp,
                       float* __restrict__ A) {
  const int bh = blockIdx.x;
  const int b = bh >> 3, head = bh & 7;
  const int tid = threadIdx.x;
  __shared__ float sums[80];
  if (tid < 64) {
    float s = 0.f;
    const float* pp = partialS + (size_t)bh * GC * 64 + tid;
    for (int j = 0; j < GC; ++j) s += pp[j * 64];
    sums[tid] = s;  // S[c*8+e]
  } else if (tid < 72) {
    const int e = tid - 64;
    float s = 0.f;
    const float* pp = nkp + ((size_t)b * 64 + head * 8 + e) * 64;
    for (int j = 0; j < 64; ++j) s += pp[j];
    sums[64 + e] = s;  // nk[e]
  } else if (tid < 80) {
    const int c = tid - 72;
    float s = 0.f;
    const float* pp = nqp + ((size_t)b * 64 + head * 8 + c) * 64;
    for (int j = 0; j < 64; ++j) s += pp[j];
    sums[72 + c] = s;  // nq[c]
  }
  __syncthreads();
  if (tid < 8) {
    const int c = tid;
    float tp = temp[head];
    float qd = fmaxf(sqrtf(sums[72 + c]), 1e-12f);
    float vals[8];
    float mx = -1e30f;
#pragma unroll
    for (int e = 0; e < 8; ++e) {
      float kd = fmaxf(sqrtf(sums[64 + e]), 1e-12f);
      vals[e] = sums[c * 8 + e] / (qd * kd) * tp;
      mx = fmaxf(mx, vals[e]);
    }
    float den = 0.f;
#pragma unroll
    for (int e = 0; e < 8; ++e) { vals[e] = expf(vals[e] - mx); den += vals[e]; }
#pragma unroll
    for (int e = 0; e < 8; ++e) A[bh * 64 + c * 8 + e] = vals[e] / den;
  }
}

// ---------------------------------------------------------------------------
// k_M: fold softmax(A) into W_proj -> MT[b][g][o] (transposed for s_load).
// ---------------------------------------------------------------------------
__global__ void k_M(const float* __restrict__ w_proj, const float* __restrict__ A,
                    float* __restrict__ MT) {
  const int b = blockIdx.x;
  for (int e = threadIdx.x; e < 4096; e += 256) {
    int o = e >> 6, gch = e & 63;
    int hg = gch >> 3, j = gch & 7;
    float s = 0.f;
#pragma unroll
    for (int i = 0; i < 8; ++i)
      s += w_proj[o * 64 + hg * 8 + i] * A[(b * 8 + hg) * 64 + i * 8 + j];
    MT[b * 4096 + gch * 64 + o] = s;
  }
}

// ---------------------------------------------------------------------------
// k_out: out[b][o][p] = sum_g MT[b][g][o] * vconv[b][g][p].
// Same LDS-x structure as k_pw. grid (2048, 2), block (64,4).
// ---------------------------------------------------------------------------
__global__ __launch_bounds__(256) void k_out(const float* __restrict__ vconv,
                                             const float* __restrict__ MT,
                                             float* __restrict__ out) {
  const int p0 = blockIdx.x * 64;
  const int b = blockIdx.y;
  const int tx = threadIdx.x;
  const int og = threadIdx.y;
  __shared__ __align__(16) float vl[64][64];
  const float* vb = vconv + ((size_t)b * 64) * NPOS + p0;
  const int tid = og * 64 + tx;
#pragma unroll
  for (int r = 0; r < 4; ++r) {
    int idx = r * 256 + tid;
    int ch = idx >> 4;
    int j4 = (idx & 15) * 4;
    *(float4*)&vl[ch][j4] = *(const float4*)&vb[(size_t)ch * NPOS + j4];
  }
  __syncthreads();
  float acc[16];
#pragma unroll
  for (int o = 0; o < 16; ++o) acc[o] = 0.f;
  const float* Mb = MT + b * 4096 + og * 16;
  for (int g = 0; g < 64; ++g) {
    float vv = vl[g][tx];
    const float* wr = Mb + (g << 6);  // wave-uniform -> s_load
#pragma unroll
    for (int o = 0; o < 16; ++o) acc[o] = fmaf(wr[o], vv, acc[o]);
  }
  float* ob = out + ((size_t)b * 64 + og * 16) * NPOS + p0 + tx;
#pragma unroll
  for (int o = 0; o < 16; ++o) ob[(size_t)o * NPOS] = acc[o];
}

extern "C" void kernel_launch(void* const* d_in, const int* in_sizes, int n_in,
                              void* d_out, int out_size, void* d_ws, size_t ws_size,
                              hipStream_t stream) {
  const float* x      = (const float*)d_in[0];
  const float* w_qkv  = (const float*)d_in[1];
  const float* w_dw   = (const float*)d_in[2];
  const float* temp   = (const float*)d_in[3];
  const float* w_proj = (const float*)d_in[4];
  float* out = (float*)d_out;   // also used as pre-conv staging per group
  float* ws  = (float*)d_ws;

  // workspace layout (floats) — ~135 MB (ws_size ~256 MiB: r9/r10 proven fit)
  float* conv_buf = ws;                       // qconv, later vconv (67 MB)
  float* kconv    = conv_buf + 16777216ull;   // 67 MB
  float* nqp      = kconv + 16777216ull;      // 8,192
  float* nkp      = nqp + 8192ull;            // 8,192
  float* partialS = nkp + 8192ull;            // 16*GC*64 = 131,072
  float* Abuf     = partialS + 131072ull;     // 1,024
  float* MTbuf    = Abuf + 1024ull;           // 8,192
  float* wTbuf    = MTbuf + 8192ull;          // 12,288

  k_prep<<<2, 256, 0, stream>>>(w_qkv, wTbuf);
  // q group: pointwise -> d_out, depthwise -> conv_buf (+ nq partials)
  k_pw<<<dim3(2048, 2), dim3(64, 4), 0, stream>>>(x, wTbuf, out);
  k_dw<<<8192, dim3(32, 8), 0, stream>>>(out, w_dw, conv_buf, nqp, 0);
  // k group: pointwise -> d_out, depthwise -> kconv (+ nk partials)
  k_pw<<<dim3(2048, 2), dim3(64, 4), 0, stream>>>(x, wTbuf + 4096, out);
  k_dw<<<8192, dim3(32, 8), 0, stream>>>(out, w_dw, kconv, nkp, 1);
  // Gram + attention matrix + folded projection matrix
  k_gramS<<<dim3(GC, 16), 256, 0, stream>>>(conv_buf, kconv, partialS);
  k_attn<<<16, 128, 0, stream>>>(partialS, nqp, nkp, temp, Abuf);
  k_M<<<2, 256, 0, stream>>>(w_proj, Abuf, MTbuf);
  // v group: pointwise -> d_out, depthwise -> conv_buf, apply M -> d_out
  k_pw<<<dim3(2048, 2), dim3(64, 4), 0, stream>>>(x, wTbuf + 8192, out);
  k_dw<<<8192, dim3(32, 8), 0, stream>>>(out, w_dw, conv_buf, nullptr, 2);
  k_out<<<dim3(2048, 2), dim3(64, 4), 0, stream>>>(conv_buf, MTbuf, out);
}

// Round 14
// 294.506 us; speedup vs baseline: 2.0988x; 2.0988x over previous
//
#include <hip/hip_runtime.h>
#include <math.h>

#define NPOS 131072  // 8*128*128 spatial positions per (b, channel)
#define GC 128       // gram chunks per (b,head); chunk = 1024 positions

// ---------------------------------------------------------------------------
// k_prep: transpose w_qkv [192 out][64 in] -> wT[3 g][64 k][64 o].
// ---------------------------------------------------------------------------
__global__ void k_prep(const float* __restrict__ w_qkv, float* __restrict__ wT) {
  for (int i = blockIdx.x * 256 + threadIdx.x; i < 12288; i += 512) {
    int g = i >> 12, r = i & 4095, k = r >> 6, o = r & 63;
    wT[i] = w_qkv[(g * 64 + o) * 64 + k];
  }
}

// ---------------------------------------------------------------------------
// k_pw: pre[b][o][p] = sum_k wTg[k][o] * x[b][k][p].  grid (512, 2), block 256.
// Explicit 2-pass (32 acc each, half-loop NOT unrolled so the compiler can't
// re-merge+fission it — r11/r12 lesson) + 8-deep x prefetch so ~8 loads are
// in flight under 256 FMAs (r11: fission to A~16 left latency exposed,
// VALUBusy 25%). Weights via wave-uniform s_load (separate counter from the
// vmem x path; r13's LDS-x died on the shared lgkmcnt between ds_read+s_load).
// ---------------------------------------------------------------------------
__global__ __launch_bounds__(256) void k_pw(const float* __restrict__ x,
                                            const float* __restrict__ wTg,
                                            float* __restrict__ pre) {
  const int p = blockIdx.x * 256 + threadIdx.x;
  const int b = blockIdx.y;
  const float* xb = x + ((size_t)b * 64) * NPOS + p;
#pragma unroll 1
  for (int half = 0; half < 2; ++half) {
    float acc[32];
#pragma unroll
    for (int o = 0; o < 32; ++o) acc[o] = 0.f;
    float xf[8], xn[8];
#pragma unroll
    for (int j = 0; j < 8; ++j) xf[j] = xb[(size_t)j * NPOS];
#pragma unroll 1
    for (int k0 = 0; k0 < 64; k0 += 8) {
      if (k0 + 8 < 64) {
#pragma unroll
        for (int j = 0; j < 8; ++j) xn[j] = xb[(size_t)(k0 + 8 + j) * NPOS];
      }
#pragma unroll
      for (int j = 0; j < 8; ++j) {
        const float* wr = wTg + ((k0 + j) << 6) + half * 32;  // uniform -> s_load
#pragma unroll
        for (int o = 0; o < 32; ++o) acc[o] = fmaf(wr[o], xf[j], acc[o]);
      }
#pragma unroll
      for (int j = 0; j < 8; ++j) xf[j] = xn[j];
    }
    float* ob = pre + ((size_t)b * 64 + half * 32) * NPOS + p;
#pragma unroll
    for (int o = 0; o < 32; ++o) ob[(size_t)o * NPOS] = acc[o];
  }
}

// ---------------------------------------------------------------------------
// stage_tile: one channel's halo tile -> LDS t[10][10][40]. float4 center,
// scalar edges, zero d-halo planes.
// ---------------------------------------------------------------------------
__device__ __forceinline__ void stage_tile(float (*t)[10][40], const float* __restrict__ in,
                                           int h0, int w0, int tid) {
  for (int i = tid; i < 800; i += 256) {
    int j = i & 7, row = i >> 3;
    int h = row % 10, dpl = row / 10;
    int dd = dpl - 1, hh = h0 + h - 1;
    float4 v = make_float4(0.f, 0.f, 0.f, 0.f);
    if (dd >= 0 && dd < 8 && hh >= 0 && hh < 128)
      v = *(const float4*)&in[((size_t)dd * 128 + hh) * 128 + (w0 + j * 4)];
    *(float4*)&t[dpl][h][4 + j * 4] = v;
  }
  for (int i = tid; i < 200; i += 256) {
    int side = i & 1, row = i >> 1;
    int h = row % 10, dpl = row / 10;
    int dd = dpl - 1, hh = h0 + h - 1;
    int ww = side ? (w0 + 32) : (w0 - 1);
    float v = 0.f;
    if (dd >= 0 && dd < 8 && hh >= 0 && hh < 128 && ww >= 0 && ww < 128)
      v = in[((size_t)dd * 128 + hh) * 128 + ww];
    t[dpl][h][side ? 36 : 3] = v;
  }
}

// ---------------------------------------------------------------------------
// conv_droll: d-rolling 3x3x3 conv: 90 LDS reads, 216 FMA for 8 d-outputs.
// ---------------------------------------------------------------------------
__device__ __forceinline__ void conv_droll(const float (*t)[10][40], const float* wk,
                                           int hl, int wl, float* acc) {
#pragma unroll
  for (int d = 0; d < 8; ++d) acc[d] = 0.f;
#pragma unroll
  for (int dpl = 0; dpl < 10; ++dpl) {
#pragma unroll
    for (int kh = 0; kh < 3; ++kh) {
#pragma unroll
      for (int kw = 0; kw < 3; ++kw) {
        float f = t[dpl][hl + kh][3 + wl + kw];
#pragma unroll
        for (int kd = 0; kd < 3; ++kd) {
          const int d = dpl - kd;
          if (d >= 0 && d < 8)
            acc[d] = fmaf(f, wk[(kd * 3 + kh) * 3 + kw], acc[d]);
        }
      }
    }
  }
}

// ---------------------------------------------------------------------------
// k_dw: depthwise 3x3x3 SAME on a 64-channel group. Flat grid 8192,
// XCD-swizzled. block (32, 8). Optional sum-of-squares partials -> nsq.
// ---------------------------------------------------------------------------
__global__ __launch_bounds__(256) void k_dw(const float* __restrict__ pre,
                                            const float* __restrict__ w_dw,
                                            float* __restrict__ conv,
                                            float* __restrict__ nsq, int g) {
  const int id = blockIdx.x;
  const int sid = (id & 7) * 1024 + (id >> 3);
  const int z = sid >> 6, r = sid & 63, by = r >> 2, bx = r & 3;
  const int b = z >> 6;
  const int c = z & 63;
  const int h0 = by * 8;
  const int w0 = bx * 32;
  __shared__ float t[10][10][40];
  __shared__ float red[4];
  const int tid = threadIdx.y * 32 + threadIdx.x;
  stage_tile(t, pre + ((size_t)b * 64 + c) * NPOS, h0, w0, tid);
  float wk[27];
#pragma unroll
  for (int i = 0; i < 27; ++i) wk[i] = w_dw[(g * 64 + c) * 27 + i];
  __syncthreads();
  const int wl = threadIdx.x, hl = threadIdx.y;
  float acc[8];
  conv_droll(t, wk, hl, wl, acc);
  float* outp = conv + ((size_t)b * 64 + c) * NPOS + (size_t)(h0 + hl) * 128 + (w0 + wl);
  float nsum = 0.f;
#pragma unroll
  for (int d = 0; d < 8; ++d) {
    outp[(size_t)d * 16384] = acc[d];
    nsum = fmaf(acc[d], acc[d], nsum);
  }
  if (nsq) {
    const int lane = tid & 63, wv = tid >> 6;
    float v = nsum;
    v += __shfl_down(v, 32); v += __shfl_down(v, 16); v += __shfl_down(v, 8);
    v += __shfl_down(v, 4);  v += __shfl_down(v, 2);  v += __shfl_down(v, 1);
    if (lane == 0) red[wv] = v;
    __syncthreads();
    if (tid == 0) {
      const int blk = by * 4 + bx;
      nsq[((size_t)b * 64 + c) * 64 + blk] = red[0] + red[1] + red[2] + red[3];
    }
  }
}

// ---------------------------------------------------------------------------
// k_gramS: streaming Gram reduce, S[8][8] only (norms come from k_dw).
// grid (GC, 16 bh), block 256; 4 unrolled iterations of {16 loads -> 64 FMA};
// asm guards pin S. Butterfly-split reduction (63 shuffles) -> lane l holds
// wave sum of S[bitrev6(l)]. partialS[(bh*GC + chunk)*64 + c*8+e].
// ---------------------------------------------------------------------------
__global__ __launch_bounds__(256) void k_gramS(const float* __restrict__ qconv,
                                               const float* __restrict__ kconv,
                                               float* __restrict__ partialS) {
  const int chunk = blockIdx.x;   // 0..GC-1
  const int bh = blockIdx.y;      // 0..15
  const int b = bh >> 3, head = bh & 7;
  const int tid = threadIdx.x;
  const size_t base = ((size_t)b * 64 + head * 8) * NPOS + (size_t)chunk * 1024 + tid;
  const float* qb = qconv + base;
  const float* kb = kconv + base;
  float S[64];
#pragma unroll
  for (int i = 0; i < 64; ++i) S[i] = 0.f;
#pragma unroll
  for (int it = 0; it < 4; ++it) {
    const size_t off = (size_t)it * 256;
    float qv[8], kv[8];
#pragma unroll
    for (int c = 0; c < 8; ++c) qv[c] = qb[(size_t)c * NPOS + off];
#pragma unroll
    for (int e = 0; e < 8; ++e) kv[e] = kb[(size_t)e * NPOS + off];
#pragma unroll
    for (int c = 0; c < 8; ++c)
#pragma unroll
      for (int e = 0; e < 8; ++e) S[c * 8 + e] = fmaf(qv[c], kv[e], S[c * 8 + e]);
  }
#pragma unroll
  for (int i = 0; i < 64; ++i) asm volatile("" : "+v"(S[i]));  // keep S material

  const int lane = tid & 63, wv = tid >> 6;
#define BSTEP(src, dst, n, s)                                        \
  {                                                                  \
    const bool hi_ = (lane >> (s)) & 1;                              \
    _Pragma("unroll")                                                \
    for (int i_ = 0; i_ < (n); ++i_) {                               \
      float send_ = hi_ ? src[i_] : src[i_ + (n)];                   \
      float mine_ = hi_ ? src[i_ + (n)] : src[i_];                   \
      dst[i_] = mine_ + __shfl_xor(send_, 1 << (s));                 \
    }                                                                \
  }
  float v32[32], v16[16], v8[8], v4[4], v2[2], v1[1];
  BSTEP(S,   v32, 32, 0)
  BSTEP(v32, v16, 16, 1)
  BSTEP(v16, v8,   8, 2)
  BSTEP(v8,  v4,   4, 3)
  BSTEP(v4,  v2,   2, 4)
  BSTEP(v2,  v1,   1, 5)
#undef BSTEP
  const int idx = ((lane & 1) << 5) | ((lane & 2) << 3) | ((lane & 4) << 1) |
                  ((lane & 8) >> 1) | ((lane & 16) >> 3) | ((lane & 32) >> 5);
  __shared__ float red[4][64];
  red[wv][idx] = v1[0];
  __syncthreads();
  if (tid < 64) {
    float s = red[0][tid] + red[1][tid] + red[2][tid] + red[3][tid];
    partialS[((size_t)bh * GC + chunk) * 64 + tid] = s;
  }
}

// ---------------------------------------------------------------------------
// k_attn: reduce partialS (GC chunks) + nqp/nkp (64 spatial blocks),
// l2-normalize, temperature, softmax -> A[bh][c][e]. grid 16, block 128.
// ---------------------------------------------------------------------------
__global__ void k_attn(const float* __restrict__ partialS, const float* __restrict__ nqp,
                       const float* __restrict__ nkp, const float* __restrict__ temp,
                       float* __restrict__ A) {
  const int bh = blockIdx.x;
  const int b = bh >> 3, head = bh & 7;
  const int tid = threadIdx.x;
  __shared__ float sums[80];
  if (tid < 64) {
    float s = 0.f;
    const float* pp = partialS + (size_t)bh * GC * 64 + tid;
    for (int j = 0; j < GC; ++j) s += pp[j * 64];
    sums[tid] = s;  // S[c*8+e]
  } else if (tid < 72) {
    const int e = tid - 64;
    float s = 0.f;
    const float* pp = nkp + ((size_t)b * 64 + head * 8 + e) * 64;
    for (int j = 0; j < 64; ++j) s += pp[j];
    sums[64 + e] = s;  // nk[e]
  } else if (tid < 80) {
    const int c = tid - 72;
    float s = 0.f;
    const float* pp = nqp + ((size_t)b * 64 + head * 8 + c) * 64;
    for (int j = 0; j < 64; ++j) s += pp[j];
    sums[72 + c] = s;  // nq[c]
  }
  __syncthreads();
  if (tid < 8) {
    const int c = tid;
    float tp = temp[head];
    float qd = fmaxf(sqrtf(sums[72 + c]), 1e-12f);
    float vals[8];
    float mx = -1e30f;
#pragma unroll
    for (int e = 0; e < 8; ++e) {
      float kd = fmaxf(sqrtf(sums[64 + e]), 1e-12f);
      vals[e] = sums[c * 8 + e] / (qd * kd) * tp;
      mx = fmaxf(mx, vals[e]);
    }
    float den = 0.f;
#pragma unroll
    for (int e = 0; e < 8; ++e) { vals[e] = expf(vals[e] - mx); den += vals[e]; }
#pragma unroll
    for (int e = 0; e < 8; ++e) A[bh * 64 + c * 8 + e] = vals[e] / den;
  }
}

// ---------------------------------------------------------------------------
// k_M: fold softmax(A) into W_proj -> MT[b][g][o] (transposed for s_load).
// ---------------------------------------------------------------------------
__global__ void k_M(const float* __restrict__ w_proj, const float* __restrict__ A,
                    float* __restrict__ MT) {
  const int b = blockIdx.x;
  for (int e = threadIdx.x; e < 4096; e += 256) {
    int o = e >> 6, gch = e & 63;
    int hg = gch >> 3, j = gch & 7;
    float s = 0.f;
#pragma unroll
    for (int i = 0; i < 8; ++i)
      s += w_proj[o * 64 + hg * 8 + i] * A[(b * 8 + hg) * 64 + i * 8 + j];
    MT[b * 4096 + gch * 64 + o] = s;
  }
}

// ---------------------------------------------------------------------------
// k_out: out[b][o][p] = sum_g MT[b][g][o] * vconv[b][g][p].
// Same explicit 2-pass + prefetch structure as k_pw. grid (512, 2), block 256.
// ---------------------------------------------------------------------------
__global__ __launch_bounds__(256) void k_out(const float* __restrict__ vconv,
                                             const float* __restrict__ MT,
                                             float* __restrict__ out) {
  const int p = blockIdx.x * 256 + threadIdx.x;
  const int b = blockIdx.y;
  const float* vb = vconv + ((size_t)b * 64) * NPOS + p;
  const float* Mb = MT + b * 4096;
#pragma unroll 1
  for (int half = 0; half < 2; ++half) {
    float acc[32];
#pragma unroll
    for (int o = 0; o < 32; ++o) acc[o] = 0.f;
    float xf[8], xn[8];
#pragma unroll
    for (int j = 0; j < 8; ++j) xf[j] = vb[(size_t)j * NPOS];
#pragma unroll 1
    for (int k0 = 0; k0 < 64; k0 += 8) {
      if (k0 + 8 < 64) {
#pragma unroll
        for (int j = 0; j < 8; ++j) xn[j] = vb[(size_t)(k0 + 8 + j) * NPOS];
      }
#pragma unroll
      for (int j = 0; j < 8; ++j) {
        const float* wr = Mb + ((k0 + j) << 6) + half * 32;  // uniform -> s_load
#pragma unroll
        for (int o = 0; o < 32; ++o) acc[o] = fmaf(wr[o], xf[j], acc[o]);
      }
#pragma unroll
      for (int j = 0; j < 8; ++j) xf[j] = xn[j];
    }
    float* ob = out + ((size_t)b * 64 + half * 32) * NPOS + p;
#pragma unroll
    for (int o = 0; o < 32; ++o) ob[(size_t)o * NPOS] = acc[o];
  }
}

extern "C" void kernel_launch(void* const* d_in, const int* in_sizes, int n_in,
                              void* d_out, int out_size, void* d_ws, size_t ws_size,
                              hipStream_t stream) {
  const float* x      = (const float*)d_in[0];
  const float* w_qkv  = (const float*)d_in[1];
  const float* w_dw   = (const float*)d_in[2];
  const float* temp   = (const float*)d_in[3];
  const float* w_proj = (const float*)d_in[4];
  float* out = (float*)d_out;   // also used as pre-conv staging per group
  float* ws  = (float*)d_ws;

  // workspace layout (floats) — ~135 MB (ws_size ~256 MiB: r9/r10 proven fit)
  float* conv_buf = ws;                       // qconv, later vconv (67 MB)
  float* kconv    = conv_buf + 16777216ull;   // 67 MB
  float* nqp      = kconv + 16777216ull;      // 8,192
  float* nkp      = nqp + 8192ull;            // 8,192
  float* partialS = nkp + 8192ull;            // 16*GC*64 = 131,072
  float* Abuf     = partialS + 131072ull;     // 1,024
  float* MTbuf    = Abuf + 1024ull;           // 8,192
  float* wTbuf    = MTbuf + 8192ull;          // 12,288

  k_prep<<<2, 256, 0, stream>>>(w_qkv, wTbuf);
  // q group: pointwise -> d_out, depthwise -> conv_buf (+ nq partials)
  k_pw<<<dim3(512, 2), 256, 0, stream>>>(x, wTbuf, out);
  k_dw<<<8192, dim3(32, 8), 0, stream>>>(out, w_dw, conv_buf, nqp, 0);
  // k group: pointwise -> d_out, depthwise -> kconv (+ nk partials)
  k_pw<<<dim3(512, 2), 256, 0, stream>>>(x, wTbuf + 4096, out);
  k_dw<<<8192, dim3(32, 8), 0, stream>>>(out, w_dw, kconv, nkp, 1);
  // Gram + attention matrix + folded projection matrix
  k_gramS<<<dim3(GC, 16), 256, 0, stream>>>(conv_buf, kconv, partialS);
  k_attn<<<16, 128, 0, stream>>>(partialS, nqp, nkp, temp, Abuf);
  k_M<<<2, 256, 0, stream>>>(w_proj, Abuf, MTbuf);
  // v group: pointwise -> d_out, depthwise -> conv_buf, apply M -> d_out
  k_pw<<<dim3(512, 2), 256, 0, stream>>>(x, wTbuf + 8192, out);
  k_dw<<<8192, dim3(32, 8), 0, stream>>>(out, w_dw, conv_buf, nullptr, 2);
  k_out<<<dim3(512, 2), 256, 0, stream>>>(conv_buf, MTbuf, out);
}

// Round 15
// 235.068 us; speedup vs baseline: 2.6295x; 1.2529x over previous
//
#include <hip/hip_runtime.h>
#include <math.h>

#define NPOS 131072  // 8*128*128 spatial positions per (b, channel)
#define GC 128       // gram chunks per (b,head); chunk = 1024 positions

typedef __attribute__((ext_vector_type(8))) short short8v;  // 8 bf16 (4 VGPR)
typedef __attribute__((ext_vector_type(4))) float f32x4;    // 4 fp32 acc

// split fp32 -> bf16 hi + bf16 lo (x ~= hi + lo, lo residual ~2^-16 |x|)
__device__ __forceinline__ void bf16split(float x, unsigned short& hi, unsigned short& lo) {
  unsigned u = __float_as_uint(x);
  hi = (unsigned short)(u >> 16);
  float hif = __uint_as_float(u & 0xffff0000u);
  float l = x - hif;  // exact
  lo = (unsigned short)(__float_as_uint(l) >> 16);
}

// ---------------------------------------------------------------------------
// k_prep: split w_qkv [192 out][64 in] into A-fragment-layout bf16 hi/lo.
// Frag element (g,ot,ks,l,j) <-> W[g*64 + ot*16 + (l&15)][ks*32 + (l>>4)*8 + j].
// idx = ((g*4+ot)*2+ks)*512 + l*8 + j.  12288 items, grid 48 x 256.
// ---------------------------------------------------------------------------
__global__ void k_prep(const float* __restrict__ w_qkv, unsigned short* __restrict__ whi,
                       unsigned short* __restrict__ wlo) {
  int idx = blockIdx.x * 256 + threadIdx.x;
  if (idx < 12288) {
    int j = idx & 7, l = (idx >> 3) & 63, ks = (idx >> 9) & 1, ot = (idx >> 10) & 3,
        g = idx >> 12;
    int out = ot * 16 + (l & 15);
    int k = ks * 32 + (l >> 4) * 8 + j;
    bf16split(w_qkv[(g * 64 + out) * 64 + k], whi[idx], wlo[idx]);
  }
}

// ---------------------------------------------------------------------------
// k_pw_mfma: pre[b][o][p] = sum_k W[o][k] x[b][k][p] on the MATRIX pipe.
// 3-term bf16 hi/lo split (fp32-grade accuracy). Per wave: 64 positions as
// 4 p-tiles; A-frags (16 = 4 ot x 2 ks x hi/lo) resident. K-layout errors
// cancel (same mapping for A and B); C/D mapping is the m89-verified
// col=lane&15, row=(lane>>4)*4+reg. grid (512, 2), block 256 (4 waves).
// ---------------------------------------------------------------------------
__global__ __launch_bounds__(256) void k_pw_mfma(const float* __restrict__ x,
                                                 const unsigned short* __restrict__ whi,
                                                 const unsigned short* __restrict__ wlo,
                                                 float* __restrict__ pre) {
  const int b = blockIdx.y;
  const int lane = threadIdx.x & 63;
  const int wid = threadIdx.x >> 6;
  const int p0 = blockIdx.x * 256 + wid * 64;
  short8v ahi[4][2], alo[4][2];
#pragma unroll
  for (int ot = 0; ot < 4; ++ot)
#pragma unroll
    for (int ks = 0; ks < 2; ++ks) {
      int fi = ((ot * 2 + ks) * 64 + lane) * 8;
      ahi[ot][ks] = *(const short8v*)&whi[fi];
      alo[ot][ks] = *(const short8v*)&wlo[fi];
    }
  const int prow = lane & 15, kgrp = lane >> 4;
  const float* xb = x + ((size_t)b * 64 + kgrp * 8) * NPOS;
#pragma unroll
  for (int pt = 0; pt < 4; ++pt) {
    const int p = p0 + pt * 16 + prow;
    float xv[16];
#pragma unroll
    for (int ks = 0; ks < 2; ++ks)
#pragma unroll
      for (int j = 0; j < 8; ++j)
        xv[ks * 8 + j] = xb[(size_t)(ks * 32 + j) * NPOS + p];
    short8v bh[2], bl[2];
#pragma unroll
    for (int ks = 0; ks < 2; ++ks)
#pragma unroll
      for (int j = 0; j < 8; ++j) {
        unsigned short h, lo16;
        bf16split(xv[ks * 8 + j], h, lo16);
        bh[ks][j] = (short)h;
        bl[ks][j] = (short)lo16;
      }
#pragma unroll
    for (int ot = 0; ot < 4; ++ot) {
      f32x4 D = {0.f, 0.f, 0.f, 0.f};
#pragma unroll
      for (int ks = 0; ks < 2; ++ks) {
        D = __builtin_amdgcn_mfma_f32_16x16x32_bf16(ahi[ot][ks], bh[ks], D, 0, 0, 0);
        D = __builtin_amdgcn_mfma_f32_16x16x32_bf16(ahi[ot][ks], bl[ks], D, 0, 0, 0);
        D = __builtin_amdgcn_mfma_f32_16x16x32_bf16(alo[ot][ks], bh[ks], D, 0, 0, 0);
      }
      float* ob = pre + ((size_t)b * 64 + ot * 16 + kgrp * 4) * NPOS + p;
#pragma unroll
      for (int jj = 0; jj < 4; ++jj) ob[(size_t)jj * NPOS] = D[jj];
    }
  }
}

// ---------------------------------------------------------------------------
// stage_tile: one channel's halo tile -> LDS t[10][10][40]. float4 center,
// scalar edges, zero d-halo planes.
// ---------------------------------------------------------------------------
__device__ __forceinline__ void stage_tile(float (*t)[10][40], const float* __restrict__ in,
                                           int h0, int w0, int tid) {
  for (int i = tid; i < 800; i += 256) {
    int j = i & 7, row = i >> 3;
    int h = row % 10, dpl = row / 10;
    int dd = dpl - 1, hh = h0 + h - 1;
    float4 v = make_float4(0.f, 0.f, 0.f, 0.f);
    if (dd >= 0 && dd < 8 && hh >= 0 && hh < 128)
      v = *(const float4*)&in[((size_t)dd * 128 + hh) * 128 + (w0 + j * 4)];
    *(float4*)&t[dpl][h][4 + j * 4] = v;
  }
  for (int i = tid; i < 200; i += 256) {
    int side = i & 1, row = i >> 1;
    int h = row % 10, dpl = row / 10;
    int dd = dpl - 1, hh = h0 + h - 1;
    int ww = side ? (w0 + 32) : (w0 - 1);
    float v = 0.f;
    if (dd >= 0 && dd < 8 && hh >= 0 && hh < 128 && ww >= 0 && ww < 128)
      v = in[((size_t)dd * 128 + hh) * 128 + ww];
    t[dpl][h][side ? 36 : 3] = v;
  }
}

// ---------------------------------------------------------------------------
// conv_droll: d-rolling 3x3x3 conv: 90 LDS reads, 216 FMA for 8 d-outputs.
// ---------------------------------------------------------------------------
__device__ __forceinline__ void conv_droll(const float (*t)[10][40], const float* wk,
                                           int hl, int wl, float* acc) {
#pragma unroll
  for (int d = 0; d < 8; ++d) acc[d] = 0.f;
#pragma unroll
  for (int dpl = 0; dpl < 10; ++dpl) {
#pragma unroll
    for (int kh = 0; kh < 3; ++kh) {
#pragma unroll
      for (int kw = 0; kw < 3; ++kw) {
        float f = t[dpl][hl + kh][3 + wl + kw];
#pragma unroll
        for (int kd = 0; kd < 3; ++kd) {
          const int d = dpl - kd;
          if (d >= 0 && d < 8)
            acc[d] = fmaf(f, wk[(kd * 3 + kh) * 3 + kw], acc[d]);
        }
      }
    }
  }
}

// ---------------------------------------------------------------------------
// k_dw: depthwise 3x3x3 SAME on a 64-channel group. Flat grid 8192,
// XCD-swizzled. block (32, 8). Optional sum-of-squares partials -> nsq.
// ---------------------------------------------------------------------------
__global__ __launch_bounds__(256) void k_dw(const float* __restrict__ pre,
                                            const float* __restrict__ w_dw,
                                            float* __restrict__ conv,
                                            float* __restrict__ nsq, int g) {
  const int id = blockIdx.x;
  const int sid = (id & 7) * 1024 + (id >> 3);
  const int z = sid >> 6, r = sid & 63, by = r >> 2, bx = r & 3;
  const int b = z >> 6;
  const int c = z & 63;
  const int h0 = by * 8;
  const int w0 = bx * 32;
  __shared__ float t[10][10][40];
  __shared__ float red[4];
  const int tid = threadIdx.y * 32 + threadIdx.x;
  stage_tile(t, pre + ((size_t)b * 64 + c) * NPOS, h0, w0, tid);
  float wk[27];
#pragma unroll
  for (int i = 0; i < 27; ++i) wk[i] = w_dw[(g * 64 + c) * 27 + i];
  __syncthreads();
  const int wl = threadIdx.x, hl = threadIdx.y;
  float acc[8];
  conv_droll(t, wk, hl, wl, acc);
  float* outp = conv + ((size_t)b * 64 + c) * NPOS + (size_t)(h0 + hl) * 128 + (w0 + wl);
  float nsum = 0.f;
#pragma unroll
  for (int d = 0; d < 8; ++d) {
    outp[(size_t)d * 16384] = acc[d];
    nsum = fmaf(acc[d], acc[d], nsum);
  }
  if (nsq) {
    const int lane = tid & 63, wv = tid >> 6;
    float v = nsum;
    v += __shfl_down(v, 32); v += __shfl_down(v, 16); v += __shfl_down(v, 8);
    v += __shfl_down(v, 4);  v += __shfl_down(v, 2);  v += __shfl_down(v, 1);
    if (lane == 0) red[wv] = v;
    __syncthreads();
    if (tid == 0) {
      const int blk = by * 4 + bx;
      nsq[((size_t)b * 64 + c) * 64 + blk] = red[0] + red[1] + red[2] + red[3];
    }
  }
}

// ---------------------------------------------------------------------------
// k_gramS: streaming Gram reduce, S[8][8] only (norms come from k_dw).
// grid (GC, 16 bh), block 256; 4 unrolled iterations of {16 loads -> 64 FMA};
// asm guards pin S. Butterfly-split reduction (63 shuffles) -> lane l holds
// wave sum of S[bitrev6(l)]. partialS[(bh*GC + chunk)*64 + c*8+e].
// ---------------------------------------------------------------------------
__global__ __launch_bounds__(256) void k_gramS(const float* __restrict__ qconv,
                                               const float* __restrict__ kconv,
                                               float* __restrict__ partialS) {
  const int chunk = blockIdx.x;   // 0..GC-1
  const int bh = blockIdx.y;      // 0..15
  const int b = bh >> 3, head = bh & 7;
  const int tid = threadIdx.x;
  const size_t base = ((size_t)b * 64 + head * 8) * NPOS + (size_t)chunk * 1024 + tid;
  const float* qb = qconv + base;
  const float* kb = kconv + base;
  float S[64];
#pragma unroll
  for (int i = 0; i < 64; ++i) S[i] = 0.f;
#pragma unroll
  for (int it = 0; it < 4; ++it) {
    const size_t off = (size_t)it * 256;
    float qv[8], kv[8];
#pragma unroll
    for (int c = 0; c < 8; ++c) qv[c] = qb[(size_t)c * NPOS + off];
#pragma unroll
    for (int e = 0; e < 8; ++e) kv[e] = kb[(size_t)e * NPOS + off];
#pragma unroll
    for (int c = 0; c < 8; ++c)
#pragma unroll
      for (int e = 0; e < 8; ++e) S[c * 8 + e] = fmaf(qv[c], kv[e], S[c * 8 + e]);
  }
#pragma unroll
  for (int i = 0; i < 64; ++i) asm volatile("" : "+v"(S[i]));  // keep S material

  const int lane = tid & 63, wv = tid >> 6;
#define BSTEP(src, dst, n, s)                                        \
  {                                                                  \
    const bool hi_ = (lane >> (s)) & 1;                              \
    _Pragma("unroll")                                                \
    for (int i_ = 0; i_ < (n); ++i_) {                               \
      float send_ = hi_ ? src[i_] : src[i_ + (n)];                   \
      float mine_ = hi_ ? src[i_ + (n)] : src[i_];                   \
      dst[i_] = mine_ + __shfl_xor(send_, 1 << (s));                 \
    }                                                                \
  }
  float v32[32], v16[16], v8[8], v4[4], v2[2], v1[1];
  BSTEP(S,   v32, 32, 0)
  BSTEP(v32, v16, 16, 1)
  BSTEP(v16, v8,   8, 2)
  BSTEP(v8,  v4,   4, 3)
  BSTEP(v4,  v2,   2, 4)
  BSTEP(v2,  v1,   1, 5)
#undef BSTEP
  const int idx = ((lane & 1) << 5) | ((lane & 2) << 3) | ((lane & 4) << 1) |
                  ((lane & 8) >> 1) | ((lane & 16) >> 3) | ((lane & 32) >> 5);
  __shared__ float red[4][64];
  red[wv][idx] = v1[0];
  __syncthreads();
  if (tid < 64) {
    float s = red[0][tid] + red[1][tid] + red[2][tid] + red[3][tid];
    partialS[((size_t)bh * GC + chunk) * 64 + tid] = s;
  }
}

// ---------------------------------------------------------------------------
// k_attn: reduce partialS (GC chunks) + nqp/nkp (64 spatial blocks),
// l2-normalize, temperature, softmax -> A[bh][c][e]. grid 16, block 128.
// ---------------------------------------------------------------------------
__global__ void k_attn(const float* __restrict__ partialS, const float* __restrict__ nqp,
                       const float* __restrict__ nkp, const float* __restrict__ temp,
                       float* __restrict__ A) {
  const int bh = blockIdx.x;
  const int b = bh >> 3, head = bh & 7;
  const int tid = threadIdx.x;
  __shared__ float sums[80];
  if (tid < 64) {
    float s = 0.f;
    const float* pp = partialS + (size_t)bh * GC * 64 + tid;
    for (int j = 0; j < GC; ++j) s += pp[j * 64];
    sums[tid] = s;  // S[c*8+e]
  } else if (tid < 72) {
    const int e = tid - 64;
    float s = 0.f;
    const float* pp = nkp + ((size_t)b * 64 + head * 8 + e) * 64;
    for (int j = 0; j < 64; ++j) s += pp[j];
    sums[64 + e] = s;  // nk[e]
  } else if (tid < 80) {
    const int c = tid - 72;
    float s = 0.f;
    const float* pp = nqp + ((size_t)b * 64 + head * 8 + c) * 64;
    for (int j = 0; j < 64; ++j) s += pp[j];
    sums[72 + c] = s;  // nq[c]
  }
  __syncthreads();
  if (tid < 8) {
    const int c = tid;
    float tp = temp[head];
    float qd = fmaxf(sqrtf(sums[72 + c]), 1e-12f);
    float vals[8];
    float mx = -1e30f;
#pragma unroll
    for (int e = 0; e < 8; ++e) {
      float kd = fmaxf(sqrtf(sums[64 + e]), 1e-12f);
      vals[e] = sums[c * 8 + e] / (qd * kd) * tp;
      mx = fmaxf(mx, vals[e]);
    }
    float den = 0.f;
#pragma unroll
    for (int e = 0; e < 8; ++e) { vals[e] = expf(vals[e] - mx); den += vals[e]; }
#pragma unroll
    for (int e = 0; e < 8; ++e) A[bh * 64 + c * 8 + e] = vals[e] / den;
  }
}

// ---------------------------------------------------------------------------
// k_M: M_b = W_proj x blockdiag(softmax A_b), written directly in A-fragment
// bf16 hi/lo layout for k_out_mfma. grid 2, block 256 (4096 frag elements/b).
// ---------------------------------------------------------------------------
__global__ void k_M(const float* __restrict__ w_proj, const float* __restrict__ A,
                    unsigned short* __restrict__ Mhi, unsigned short* __restrict__ Mlo) {
  const int b = blockIdx.x;
  for (int e = threadIdx.x; e < 4096; e += 256) {
    int j = e & 7, l = (e >> 3) & 63, ks = (e >> 9) & 1, ot = (e >> 10) & 3;
    int out = ot * 16 + (l & 15);
    int gch = ks * 32 + (l >> 4) * 8 + j;
    int hg = gch >> 3, jj = gch & 7;
    float s = 0.f;
#pragma unroll
    for (int i = 0; i < 8; ++i)
      s += w_proj[out * 64 + hg * 8 + i] * A[(b * 8 + hg) * 64 + i * 8 + jj];
    bf16split(s, Mhi[b * 4096 + e], Mlo[b * 4096 + e]);
  }
}

// ---------------------------------------------------------------------------
// k_out_mfma: out[b][o][p] = sum_g M_b[o][g] vconv[b][g][p]. Same MFMA
// structure as k_pw_mfma with per-batch M fragments. grid (512, 2), block 256.
// ---------------------------------------------------------------------------
__global__ __launch_bounds__(256) void k_out_mfma(const float* __restrict__ vconv,
                                                  const unsigned short* __restrict__ Mhi,
                                                  const unsigned short* __restrict__ Mlo,
                                                  float* __restrict__ out) {
  const int b = blockIdx.y;
  const int lane = threadIdx.x & 63;
  const int wid = threadIdx.x >> 6;
  const int p0 = blockIdx.x * 256 + wid * 64;
  short8v ahi[4][2], alo[4][2];
#pragma unroll
  for (int ot = 0; ot < 4; ++ot)
#pragma unroll
    for (int ks = 0; ks < 2; ++ks) {
      int fi = b * 4096 + ((ot * 2 + ks) * 64 + lane) * 8;
      ahi[ot][ks] = *(const short8v*)&Mhi[fi];
      alo[ot][ks] = *(const short8v*)&Mlo[fi];
    }
  const int prow = lane & 15, kgrp = lane >> 4;
  const float* vb = vconv + ((size_t)b * 64 + kgrp * 8) * NPOS;
#pragma unroll
  for (int pt = 0; pt < 4; ++pt) {
    const int p = p0 + pt * 16 + prow;
    float xv[16];
#pragma unroll
    for (int ks = 0; ks < 2; ++ks)
#pragma unroll
      for (int j = 0; j < 8; ++j)
        xv[ks * 8 + j] = vb[(size_t)(ks * 32 + j) * NPOS + p];
    short8v bh[2], bl[2];
#pragma unroll
    for (int ks = 0; ks < 2; ++ks)
#pragma unroll
      for (int j = 0; j < 8; ++j) {
        unsigned short h, lo16;
        bf16split(xv[ks * 8 + j], h, lo16);
        bh[ks][j] = (short)h;
        bl[ks][j] = (short)lo16;
      }
#pragma unroll
    for (int ot = 0; ot < 4; ++ot) {
      f32x4 D = {0.f, 0.f, 0.f, 0.f};
#pragma unroll
      for (int ks = 0; ks < 2; ++ks) {
        D = __builtin_amdgcn_mfma_f32_16x16x32_bf16(ahi[ot][ks], bh[ks], D, 0, 0, 0);
        D = __builtin_amdgcn_mfma_f32_16x16x32_bf16(ahi[ot][ks], bl[ks], D, 0, 0, 0);
        D = __builtin_amdgcn_mfma_f32_16x16x32_bf16(alo[ot][ks], bh[ks], D, 0, 0, 0);
      }
      float* ob = out + ((size_t)b * 64 + ot * 16 + kgrp * 4) * NPOS + p;
#pragma unroll
      for (int jj = 0; jj < 4; ++jj) ob[(size_t)jj * NPOS] = D[jj];
    }
  }
}

extern "C" void kernel_launch(void* const* d_in, const int* in_sizes, int n_in,
                              void* d_out, int out_size, void* d_ws, size_t ws_size,
                              hipStream_t stream) {
  const float* x      = (const float*)d_in[0];
  const float* w_qkv  = (const float*)d_in[1];
  const float* w_dw   = (const float*)d_in[2];
  const float* temp   = (const float*)d_in[3];
  const float* w_proj = (const float*)d_in[4];
  float* out = (float*)d_out;   // also used as pre-conv staging per group
  float* ws  = (float*)d_ws;

  // workspace layout — ~135 MB (ws_size ~256 MiB: r9/r10 proven fit)
  float* conv_buf = ws;                       // qconv, later vconv (67 MB)
  float* kconv    = conv_buf + 16777216ull;   // 67 MB
  float* nqp      = kconv + 16777216ull;      // 8,192
  float* nkp      = nqp + 8192ull;            // 8,192
  float* partialS = nkp + 8192ull;            // 16*GC*64 = 131,072
  float* Abuf     = partialS + 131072ull;     // 1,024
  unsigned short* whi = (unsigned short*)(Abuf + 1024ull);  // 12,288 us
  unsigned short* wlo = whi + 12288ull;                     // 12,288 us
  unsigned short* Mhi = wlo + 12288ull;                     // 8,192 us
  unsigned short* Mlo = Mhi + 8192ull;                      // 8,192 us

  k_prep<<<48, 256, 0, stream>>>(w_qkv, whi, wlo);
  // q group: pointwise (MFMA) -> d_out, depthwise -> conv_buf (+ nq partials)
  k_pw_mfma<<<dim3(512, 2), 256, 0, stream>>>(x, whi, wlo, out);
  k_dw<<<8192, dim3(32, 8), 0, stream>>>(out, w_dw, conv_buf, nqp, 0);
  // k group: pointwise -> d_out, depthwise -> kconv (+ nk partials)
  k_pw_mfma<<<dim3(512, 2), 256, 0, stream>>>(x, whi + 4096, wlo + 4096, out);
  k_dw<<<8192, dim3(32, 8), 0, stream>>>(out, w_dw, kconv, nkp, 1);
  // Gram + attention matrix + folded projection matrix (frag layout)
  k_gramS<<<dim3(GC, 16), 256, 0, stream>>>(conv_buf, kconv, partialS);
  k_attn<<<16, 128, 0, stream>>>(partialS, nqp, nkp, temp, Abuf);
  k_M<<<2, 256, 0, stream>>>(w_proj, Abuf, Mhi, Mlo);
  // v group: pointwise -> d_out, depthwise -> conv_buf, apply M (MFMA) -> d_out
  k_pw_mfma<<<dim3(512, 2), 256, 0, stream>>>(x, whi + 8192, wlo + 8192, out);
  k_dw<<<8192, dim3(32, 8), 0, stream>>>(out, w_dw, conv_buf, nullptr, 2);
  k_out_mfma<<<dim3(512, 2), 256, 0, stream>>>(conv_buf, Mhi, Mlo, out);
}

// Round 16
// 222.411 us; speedup vs baseline: 2.7791x; 1.0569x over previous
//
#include <hip/hip_runtime.h>
#include <math.h>

#define NPOS 131072  // 8*128*128 spatial positions per (b, channel)
#define GC 128       // gram chunks per (b,head); chunk = 1024 positions

typedef __attribute__((ext_vector_type(8))) short short8v;  // 8 bf16 (4 VGPR)
typedef __attribute__((ext_vector_type(4))) float f32x4;    // 4 fp32 acc

// split fp32 -> bf16 hi + bf16 lo (x ~= hi + lo, lo residual ~2^-16 |x|)
__device__ __forceinline__ void bf16split(float x, unsigned short& hi, unsigned short& lo) {
  unsigned u = __float_as_uint(x);
  hi = (unsigned short)(u >> 16);
  float hif = __uint_as_float(u & 0xffff0000u);
  float l = x - hif;  // exact
  lo = (unsigned short)(__float_as_uint(l) >> 16);
}

// ---------------------------------------------------------------------------
// k_prep: split w_qkv [192 out][64 in] into A-fragment-layout bf16 hi/lo.
// Frag element (g,ot,ks,l,j) <-> W[g*64 + ot*16 + (l&15)][ks*32 + (l>>4)*8 + j].
// ---------------------------------------------------------------------------
__global__ void k_prep(const float* __restrict__ w_qkv, unsigned short* __restrict__ whi,
                       unsigned short* __restrict__ wlo) {
  int idx = blockIdx.x * 256 + threadIdx.x;
  if (idx < 12288) {
    int j = idx & 7, l = (idx >> 3) & 63, ks = (idx >> 9) & 1, ot = (idx >> 10) & 3,
        g = idx >> 12;
    int out = ot * 16 + (l & 15);
    int k = ks * 32 + (l >> 4) * 8 + j;
    bf16split(w_qkv[(g * 64 + out) * 64 + k], whi[idx], wlo[idx]);
  }
}

// ---------------------------------------------------------------------------
// k_pw_mfma: pre[b][o][p] = sum_k W[o][k] x[b][k][p] on the matrix pipe,
// LDS-tiled (r15: scalar strided x loads -> latency-bound at 2.5 TB/s,
// occupancy 16%). Block = 64 positions x 64 out-ch; wave wid owns o-tile
// ot=wid (A-frags 16 VGPR). Stage x [64ch][64pos] -> LDS [64][66] (float4
// coalesced loads, ~2-way-free ds). Inner loop is ds_read->MFMA only —
// weights are VGPR-resident, so no s_load/lgkmcnt serialization (r13 bug).
// grid (2048, 2), block 256.
// ---------------------------------------------------------------------------
__global__ __launch_bounds__(256) void k_pw_mfma(const float* __restrict__ x,
                                                 const unsigned short* __restrict__ whi,
                                                 const unsigned short* __restrict__ wlo,
                                                 float* __restrict__ pre) {
  const int b = blockIdx.y;
  const int lane = threadIdx.x & 63;
  const int ot = threadIdx.x >> 6;   // wave id = o-tile
  const int p0 = blockIdx.x * 64;
  __shared__ float xl[64][66];
  // A-frags for this wave's o-tile (hi/lo x 2 ks) — loaded before staging.
  short8v ahi[2], alo[2];
#pragma unroll
  for (int ks = 0; ks < 2; ++ks) {
    int fi = ((ot * 2 + ks) * 64 + lane) * 8;
    ahi[ks] = *(const short8v*)&whi[fi];
    alo[ks] = *(const short8v*)&wlo[fi];
  }
  // stage x tile: 1024 float4, coalesced (16 consecutive f4 per channel row)
  const float* xb = x + ((size_t)b * 64) * NPOS + p0;
  const int tid = threadIdx.x;
#pragma unroll
  for (int r = 0; r < 4; ++r) {
    int idx = r * 256 + tid;          // 0..1023
    int ch = idx >> 4, f4 = idx & 15;
    float4 g = *(const float4*)&xb[(size_t)ch * NPOS + f4 * 4];
    xl[ch][f4 * 4 + 0] = g.x;
    xl[ch][f4 * 4 + 1] = g.y;
    xl[ch][f4 * 4 + 2] = g.z;
    xl[ch][f4 * 4 + 3] = g.w;
  }
  __syncthreads();
  const int prow = lane & 15, kgrp = lane >> 4;
#pragma unroll
  for (int pt = 0; pt < 4; ++pt) {
    const int pos = pt * 16 + prow;
    short8v bh[2], bl[2];
#pragma unroll
    for (int ks = 0; ks < 2; ++ks)
#pragma unroll
      for (int j = 0; j < 8; ++j) {
        unsigned short h, lo16;
        bf16split(xl[ks * 32 + kgrp * 8 + j][pos], h, lo16);
        bh[ks][j] = (short)h;
        bl[ks][j] = (short)lo16;
      }
    f32x4 D = {0.f, 0.f, 0.f, 0.f};
#pragma unroll
    for (int ks = 0; ks < 2; ++ks) {
      D = __builtin_amdgcn_mfma_f32_16x16x32_bf16(ahi[ks], bh[ks], D, 0, 0, 0);
      D = __builtin_amdgcn_mfma_f32_16x16x32_bf16(ahi[ks], bl[ks], D, 0, 0, 0);
      D = __builtin_amdgcn_mfma_f32_16x16x32_bf16(alo[ks], bh[ks], D, 0, 0, 0);
    }
    float* ob = pre + ((size_t)b * 64 + ot * 16 + kgrp * 4) * NPOS + p0 + pos;
#pragma unroll
    for (int jj = 0; jj < 4; ++jj) ob[(size_t)jj * NPOS] = D[jj];
  }
}

// ---------------------------------------------------------------------------
// stage_tile: one channel's halo tile -> LDS t[10][10][40]. float4 center,
// scalar edges, zero d-halo planes.
// ---------------------------------------------------------------------------
__device__ __forceinline__ void stage_tile(float (*t)[10][40], const float* __restrict__ in,
                                           int h0, int w0, int tid) {
  for (int i = tid; i < 800; i += 256) {
    int j = i & 7, row = i >> 3;
    int h = row % 10, dpl = row / 10;
    int dd = dpl - 1, hh = h0 + h - 1;
    float4 v = make_float4(0.f, 0.f, 0.f, 0.f);
    if (dd >= 0 && dd < 8 && hh >= 0 && hh < 128)
      v = *(const float4*)&in[((size_t)dd * 128 + hh) * 128 + (w0 + j * 4)];
    *(float4*)&t[dpl][h][4 + j * 4] = v;
  }
  for (int i = tid; i < 200; i += 256) {
    int side = i & 1, row = i >> 1;
    int h = row % 10, dpl = row / 10;
    int dd = dpl - 1, hh = h0 + h - 1;
    int ww = side ? (w0 + 32) : (w0 - 1);
    float v = 0.f;
    if (dd >= 0 && dd < 8 && hh >= 0 && hh < 128 && ww >= 0 && ww < 128)
      v = in[((size_t)dd * 128 + hh) * 128 + ww];
    t[dpl][h][side ? 36 : 3] = v;
  }
}

// ---------------------------------------------------------------------------
// conv_droll: d-rolling 3x3x3 conv: 90 LDS reads, 216 FMA for 8 d-outputs.
// ---------------------------------------------------------------------------
__device__ __forceinline__ void conv_droll(const float (*t)[10][40], const float* wk,
                                           int hl, int wl, float* acc) {
#pragma unroll
  for (int d = 0; d < 8; ++d) acc[d] = 0.f;
#pragma unroll
  for (int dpl = 0; dpl < 10; ++dpl) {
#pragma unroll
    for (int kh = 0; kh < 3; ++kh) {
#pragma unroll
      for (int kw = 0; kw < 3; ++kw) {
        float f = t[dpl][hl + kh][3 + wl + kw];
#pragma unroll
        for (int kd = 0; kd < 3; ++kd) {
          const int d = dpl - kd;
          if (d >= 0 && d < 8)
            acc[d] = fmaf(f, wk[(kd * 3 + kh) * 3 + kw], acc[d]);
        }
      }
    }
  }
}

// ---------------------------------------------------------------------------
// k_dw: depthwise 3x3x3 SAME on a 64-channel group. Flat grid 8192,
// XCD-swizzled. block (32, 8). Optional sum-of-squares partials -> nsq.
// ---------------------------------------------------------------------------
__global__ __launch_bounds__(256) void k_dw(const float* __restrict__ pre,
                                            const float* __restrict__ w_dw,
                                            float* __restrict__ conv,
                                            float* __restrict__ nsq, int g) {
  const int id = blockIdx.x;
  const int sid = (id & 7) * 1024 + (id >> 3);
  const int z = sid >> 6, r = sid & 63, by = r >> 2, bx = r & 3;
  const int b = z >> 6;
  const int c = z & 63;
  const int h0 = by * 8;
  const int w0 = bx * 32;
  __shared__ float t[10][10][40];
  __shared__ float red[4];
  const int tid = threadIdx.y * 32 + threadIdx.x;
  stage_tile(t, pre + ((size_t)b * 64 + c) * NPOS, h0, w0, tid);
  float wk[27];
#pragma unroll
  for (int i = 0; i < 27; ++i) wk[i] = w_dw[(g * 64 + c) * 27 + i];
  __syncthreads();
  const int wl = threadIdx.x, hl = threadIdx.y;
  float acc[8];
  conv_droll(t, wk, hl, wl, acc);
  float* outp = conv + ((size_t)b * 64 + c) * NPOS + (size_t)(h0 + hl) * 128 + (w0 + wl);
  float nsum = 0.f;
#pragma unroll
  for (int d = 0; d < 8; ++d) {
    outp[(size_t)d * 16384] = acc[d];
    nsum = fmaf(acc[d], acc[d], nsum);
  }
  if (nsq) {
    const int lane = tid & 63, wv = tid >> 6;
    float v = nsum;
    v += __shfl_down(v, 32); v += __shfl_down(v, 16); v += __shfl_down(v, 8);
    v += __shfl_down(v, 4);  v += __shfl_down(v, 2);  v += __shfl_down(v, 1);
    if (lane == 0) red[wv] = v;
    __syncthreads();
    if (tid == 0) {
      const int blk = by * 4 + bx;
      nsq[((size_t)b * 64 + c) * 64 + blk] = red[0] + red[1] + red[2] + red[3];
    }
  }
}

// ---------------------------------------------------------------------------
// k_gramS: streaming Gram reduce, S[8][8] only (norms come from k_dw).
// grid (GC, 16 bh), block 256; 4 unrolled iterations of {16 loads -> 64 FMA};
// asm guards pin S. Butterfly-split reduction (63 shuffles) -> lane l holds
// wave sum of S[bitrev6(l)]. partialS[(bh*GC + chunk)*64 + c*8+e].
// ---------------------------------------------------------------------------
__global__ __launch_bounds__(256) void k_gramS(const float* __restrict__ qconv,
                                               const float* __restrict__ kconv,
                                               float* __restrict__ partialS) {
  const int chunk = blockIdx.x;   // 0..GC-1
  const int bh = blockIdx.y;      // 0..15
  const int b = bh >> 3, head = bh & 7;
  const int tid = threadIdx.x;
  const size_t base = ((size_t)b * 64 + head * 8) * NPOS + (size_t)chunk * 1024 + tid;
  const float* qb = qconv + base;
  const float* kb = kconv + base;
  float S[64];
#pragma unroll
  for (int i = 0; i < 64; ++i) S[i] = 0.f;
#pragma unroll
  for (int it = 0; it < 4; ++it) {
    const size_t off = (size_t)it * 256;
    float qv[8], kv[8];
#pragma unroll
    for (int c = 0; c < 8; ++c) qv[c] = qb[(size_t)c * NPOS + off];
#pragma unroll
    for (int e = 0; e < 8; ++e) kv[e] = kb[(size_t)e * NPOS + off];
#pragma unroll
    for (int c = 0; c < 8; ++c)
#pragma unroll
      for (int e = 0; e < 8; ++e) S[c * 8 + e] = fmaf(qv[c], kv[e], S[c * 8 + e]);
  }
#pragma unroll
  for (int i = 0; i < 64; ++i) asm volatile("" : "+v"(S[i]));  // keep S material

  const int lane = tid & 63, wv = tid >> 6;
#define BSTEP(src, dst, n, s)                                        \
  {                                                                  \
    const bool hi_ = (lane >> (s)) & 1;                              \
    _Pragma("unroll")                                                \
    for (int i_ = 0; i_ < (n); ++i_) {                               \
      float send_ = hi_ ? src[i_] : src[i_ + (n)];                   \
      float mine_ = hi_ ? src[i_ + (n)] : src[i_];                   \
      dst[i_] = mine_ + __shfl_xor(send_, 1 << (s));                 \
    }                                                                \
  }
  float v32[32], v16[16], v8[8], v4[4], v2[2], v1[1];
  BSTEP(S,   v32, 32, 0)
  BSTEP(v32, v16, 16, 1)
  BSTEP(v16, v8,   8, 2)
  BSTEP(v8,  v4,   4, 3)
  BSTEP(v4,  v2,   2, 4)
  BSTEP(v2,  v1,   1, 5)
#undef BSTEP
  const int idx = ((lane & 1) << 5) | ((lane & 2) << 3) | ((lane & 4) << 1) |
                  ((lane & 8) >> 1) | ((lane & 16) >> 3) | ((lane & 32) >> 5);
  __shared__ float red[4][64];
  red[wv][idx] = v1[0];
  __syncthreads();
  if (tid < 64) {
    float s = red[0][tid] + red[1][tid] + red[2][tid] + red[3][tid];
    partialS[((size_t)bh * GC + chunk) * 64 + tid] = s;
  }
}

// ---------------------------------------------------------------------------
// k_attn: reduce partialS (GC chunks) + nqp/nkp (64 spatial blocks),
// l2-normalize, temperature, softmax -> A[bh][c][e]. grid 16, block 128.
// ---------------------------------------------------------------------------
__global__ void k_attn(const float* __restrict__ partialS, const float* __restrict__ nqp,
                       const float* __restrict__ nkp, const float* __restrict__ temp,
                       float* __restrict__ A) {
  const int bh = blockIdx.x;
  const int b = bh >> 3, head = bh & 7;
  const int tid = threadIdx.x;
  __shared__ float sums[80];
  if (tid < 64) {
    float s = 0.f;
    const float* pp = partialS + (size_t)bh * GC * 64 + tid;
    for (int j = 0; j < GC; ++j) s += pp[j * 64];
    sums[tid] = s;  // S[c*8+e]
  } else if (tid < 72) {
    const int e = tid - 64;
    float s = 0.f;
    const float* pp = nkp + ((size_t)b * 64 + head * 8 + e) * 64;
    for (int j = 0; j < 64; ++j) s += pp[j];
    sums[64 + e] = s;  // nk[e]
  } else if (tid < 80) {
    const int c = tid - 72;
    float s = 0.f;
    const float* pp = nqp + ((size_t)b * 64 + head * 8 + c) * 64;
    for (int j = 0; j < 64; ++j) s += pp[j];
    sums[72 + c] = s;  // nq[c]
  }
  __syncthreads();
  if (tid < 8) {
    const int c = tid;
    float tp = temp[head];
    float qd = fmaxf(sqrtf(sums[72 + c]), 1e-12f);
    float vals[8];
    float mx = -1e30f;
#pragma unroll
    for (int e = 0; e < 8; ++e) {
      float kd = fmaxf(sqrtf(sums[64 + e]), 1e-12f);
      vals[e] = sums[c * 8 + e] / (qd * kd) * tp;
      mx = fmaxf(mx, vals[e]);
    }
    float den = 0.f;
#pragma unroll
    for (int e = 0; e < 8; ++e) { vals[e] = expf(vals[e] - mx); den += vals[e]; }
#pragma unroll
    for (int e = 0; e < 8; ++e) A[bh * 64 + c * 8 + e] = vals[e] / den;
  }
}

// ---------------------------------------------------------------------------
// k_M: M_b = W_proj x blockdiag(softmax A_b), written directly in A-fragment
// bf16 hi/lo layout for k_out_mfma. grid 2, block 256.
// ---------------------------------------------------------------------------
__global__ void k_M(const float* __restrict__ w_proj, const float* __restrict__ A,
                    unsigned short* __restrict__ Mhi, unsigned short* __restrict__ Mlo) {
  const int b = blockIdx.x;
  for (int e = threadIdx.x; e < 4096; e += 256) {
    int j = e & 7, l = (e >> 3) & 63, ks = (e >> 9) & 1, ot = (e >> 10) & 3;
    int out = ot * 16 + (l & 15);
    int gch = ks * 32 + (l >> 4) * 8 + j;
    int hg = gch >> 3, jj = gch & 7;
    float s = 0.f;
#pragma unroll
    for (int i = 0; i < 8; ++i)
      s += w_proj[out * 64 + hg * 8 + i] * A[(b * 8 + hg) * 64 + i * 8 + jj];
    bf16split(s, Mhi[b * 4096 + e], Mlo[b * 4096 + e]);
  }
}

// ---------------------------------------------------------------------------
// k_out_mfma: out[b][o][p] = sum_g M_b[o][g] vconv[b][g][p]. Same LDS-tiled
// MFMA structure as k_pw_mfma. grid (2048, 2), block 256.
// ---------------------------------------------------------------------------
__global__ __launch_bounds__(256) void k_out_mfma(const float* __restrict__ vconv,
                                                  const unsigned short* __restrict__ Mhi,
                                                  const unsigned short* __restrict__ Mlo,
                                                  float* __restrict__ out) {
  const int b = blockIdx.y;
  const int lane = threadIdx.x & 63;
  const int ot = threadIdx.x >> 6;
  const int p0 = blockIdx.x * 64;
  __shared__ float xl[64][66];
  short8v ahi[2], alo[2];
#pragma unroll
  for (int ks = 0; ks < 2; ++ks) {
    int fi = b * 4096 + ((ot * 2 + ks) * 64 + lane) * 8;
    ahi[ks] = *(const short8v*)&Mhi[fi];
    alo[ks] = *(const short8v*)&Mlo[fi];
  }
  const float* vb = vconv + ((size_t)b * 64) * NPOS + p0;
  const int tid = threadIdx.x;
#pragma unroll
  for (int r = 0; r < 4; ++r) {
    int idx = r * 256 + tid;
    int ch = idx >> 4, f4 = idx & 15;
    float4 g = *(const float4*)&vb[(size_t)ch * NPOS + f4 * 4];
    xl[ch][f4 * 4 + 0] = g.x;
    xl[ch][f4 * 4 + 1] = g.y;
    xl[ch][f4 * 4 + 2] = g.z;
    xl[ch][f4 * 4 + 3] = g.w;
  }
  __syncthreads();
  const int prow = lane & 15, kgrp = lane >> 4;
#pragma unroll
  for (int pt = 0; pt < 4; ++pt) {
    const int pos = pt * 16 + prow;
    short8v bh[2], bl[2];
#pragma unroll
    for (int ks = 0; ks < 2; ++ks)
#pragma unroll
      for (int j = 0; j < 8; ++j) {
        unsigned short h, lo16;
        bf16split(xl[ks * 32 + kgrp * 8 + j][pos], h, lo16);
        bh[ks][j] = (short)h;
        bl[ks][j] = (short)lo16;
      }
    f32x4 D = {0.f, 0.f, 0.f, 0.f};
#pragma unroll
    for (int ks = 0; ks < 2; ++ks) {
      D = __builtin_amdgcn_mfma_f32_16x16x32_bf16(ahi[ks], bh[ks], D, 0, 0, 0);
      D = __builtin_amdgcn_mfma_f32_16x16x32_bf16(ahi[ks], bl[ks], D, 0, 0, 0);
      D = __builtin_amdgcn_mfma_f32_16x16x32_bf16(alo[ks], bh[ks], D, 0, 0, 0);
    }
    float* ob = out + ((size_t)b * 64 + ot * 16 + kgrp * 4) * NPOS + p0 + pos;
#pragma unroll
    for (int jj = 0; jj < 4; ++jj) ob[(size_t)jj * NPOS] = D[jj];
  }
}

extern "C" void kernel_launch(void* const* d_in, const int* in_sizes, int n_in,
                              void* d_out, int out_size, void* d_ws, size_t ws_size,
                              hipStream_t stream) {
  const float* x      = (const float*)d_in[0];
  const float* w_qkv  = (const float*)d_in[1];
  const float* w_dw   = (const float*)d_in[2];
  const float* temp   = (const float*)d_in[3];
  const float* w_proj = (const float*)d_in[4];
  float* out = (float*)d_out;   // also used as pre-conv staging per group
  float* ws  = (float*)d_ws;

  // workspace layout — ~135 MB (ws_size ~256 MiB: r9/r10 proven fit)
  float* conv_buf = ws;                       // qconv, later vconv (67 MB)
  float* kconv    = conv_buf + 16777216ull;   // 67 MB
  float* nqp      = kconv + 16777216ull;      // 8,192
  float* nkp      = nqp + 8192ull;            // 8,192
  float* partialS = nkp + 8192ull;            // 16*GC*64 = 131,072
  float* Abuf     = partialS + 131072ull;     // 1,024
  unsigned short* whi = (unsigned short*)(Abuf + 1024ull);  // 12,288 us
  unsigned short* wlo = whi + 12288ull;                     // 12,288 us
  unsigned short* Mhi = wlo + 12288ull;                     // 8,192 us
  unsigned short* Mlo = Mhi + 8192ull;                      // 8,192 us

  k_prep<<<48, 256, 0, stream>>>(w_qkv, whi, wlo);
  // q group: pointwise (MFMA) -> d_out, depthwise -> conv_buf (+ nq partials)
  k_pw_mfma<<<dim3(2048, 2), 256, 0, stream>>>(x, whi, wlo, out);
  k_dw<<<8192, dim3(32, 8), 0, stream>>>(out, w_dw, conv_buf, nqp, 0);
  // k group: pointwise -> d_out, depthwise -> kconv (+ nk partials)
  k_pw_mfma<<<dim3(2048, 2), 256, 0, stream>>>(x, whi + 4096, wlo + 4096, out);
  k_dw<<<8192, dim3(32, 8), 0, stream>>>(out, w_dw, kconv, nkp, 1);
  // Gram + attention matrix + folded projection matrix (frag layout)
  k_gramS<<<dim3(GC, 16), 256, 0, stream>>>(conv_buf, kconv, partialS);
  k_attn<<<16, 128, 0, stream>>>(partialS, nqp, nkp, temp, Abuf);
  k_M<<<2, 256, 0, stream>>>(w_proj, Abuf, Mhi, Mlo);
  // v group: pointwise -> d_out, depthwise -> conv_buf, apply M (MFMA) -> d_out
  k_pw_mfma<<<dim3(2048, 2), 256, 0, stream>>>(x, whi + 8192, wlo + 8192, out);
  k_dw<<<8192, dim3(32, 8), 0, stream>>>(out, w_dw, conv_buf, nullptr, 2);
  k_out_mfma<<<dim3(2048, 2), 256, 0, stream>>>(conv_buf, Mhi, Mlo, out);
}